// Round 1
// baseline (1035.419 us; speedup 1.0000x reference)
//
#include <hip/hip_runtime.h>

using u16 = unsigned short;
typedef __attribute__((ext_vector_type(8))) short bf16x8;
typedef __attribute__((ext_vector_type(4))) float f32x4;
typedef __attribute__((ext_vector_type(4))) float f4;

#define H_ 16
#define HD_ 32
#define DIMC 1024
#define NQ 2048
#define NK 2048

static constexpr float LAMBDA_INIT = 0.6192834728526787f;  // 0.8 - 0.6*exp(-1.2)
static constexpr float ONE_MINUS_LI = 1.0f - 0.6192834728526787f;
static constexpr float SCALE_ = 0.17677669529663687f;      // 32^-0.5
static constexpr float EPS_ = 1e-5f;

__device__ __forceinline__ u16 f2bf(float f) {
    union { float f; unsigned u; } v; v.f = f;
    unsigned u = v.u;
    unsigned r = (u + 0x7FFFu + ((u >> 16) & 1u)) >> 16;
    return (u16)r;
}

__device__ __forceinline__ bf16x8 load8f_bf(const float* p) {
    f4 a = *(const f4*)p;
    f4 b = *(const f4*)(p + 4);
    bf16x8 r;
    r[0] = (short)f2bf(a[0]); r[1] = (short)f2bf(a[1]);
    r[2] = (short)f2bf(a[2]); r[3] = (short)f2bf(a[3]);
    r[4] = (short)f2bf(b[0]); r[5] = (short)f2bf(b[1]);
    r[6] = (short)f2bf(b[2]); r[7] = (short)f2bf(b[3]);
    return r;
}

// C = A @ B^T.  A: M x K (f32 or bf16), B: N x K (f32). Output bf16 or f32+bias.
template<int A_IS_BF16, int OUT_IS_BF16>
__global__ __launch_bounds__(256) void gemm_bt_kernel(
    const void* __restrict__ A_, const float* __restrict__ Bw,
    void* __restrict__ C_, const float* __restrict__ bias,
    int M, int N, int K)
{
    const int lane = threadIdx.x & 63;
    const int wave = threadIdx.x >> 6;
    const int wr = wave >> 1, wc = wave & 1;
    const int l15 = lane & 15, l4 = lane >> 4;
    const int tm = blockIdx.x * 64, tn = blockIdx.y * 64;
    const int arow0 = tm + wr * 32, brow0 = tn + wc * 32;

    f32x4 acc[2][2];
    f32x4 zf = {0.f, 0.f, 0.f, 0.f};
    acc[0][0] = zf; acc[0][1] = zf; acc[1][0] = zf; acc[1][1] = zf;

    for (int k0 = 0; k0 < K; k0 += 32) {
        const int kk = k0 + 8 * l4;
        bf16x8 af[2], bfr[2];
#pragma unroll
        for (int i = 0; i < 2; ++i) {
            const int ar = arow0 + i * 16 + l15;
            if (A_IS_BF16)
                af[i] = *(const bf16x8*)((const u16*)A_ + (size_t)ar * K + kk);
            else
                af[i] = load8f_bf((const float*)A_ + (size_t)ar * K + kk);
            const int br = brow0 + i * 16 + l15;
            bfr[i] = load8f_bf(Bw + (size_t)br * K + kk);
        }
#pragma unroll
        for (int i = 0; i < 2; ++i)
#pragma unroll
            for (int j = 0; j < 2; ++j)
                acc[i][j] = __builtin_amdgcn_mfma_f32_16x16x32_bf16(af[i], bfr[j], acc[i][j], 0, 0, 0);
    }

#pragma unroll
    for (int i = 0; i < 2; ++i)
#pragma unroll
        for (int j = 0; j < 2; ++j)
#pragma unroll
            for (int r = 0; r < 4; ++r) {
                const int row = arow0 + i * 16 + l4 * 4 + r;
                const int col = brow0 + j * 16 + l15;
                const float v = acc[i][j][r];
                if (OUT_IS_BF16)
                    ((u16*)C_)[(size_t)row * N + col] = f2bf(v);
                else
                    ((float*)C_)[(size_t)row * N + col] = v + bias[col];
            }
}

// Differential flash attention + subln RMS-norm epilogue.
// Qb/Kb/Vb: bf16 [B*2048][1024].  X2 out: bf16 [B*2048][1024].
__global__ __launch_bounds__(256) void attn_kernel(
    const u16* __restrict__ Qb, const u16* __restrict__ Kb, const u16* __restrict__ Vb,
    const float* __restrict__ lq1, const float* __restrict__ lk1,
    const float* __restrict__ lq2, const float* __restrict__ lk2,
    const float* __restrict__ subln, u16* __restrict__ X2)
{
    const int lane = threadIdx.x & 63;
    const int wave = threadIdx.x >> 6;
    const int l15 = lane & 15, l4 = lane >> 4;
    const int b = blockIdx.z, h = blockIdx.y;
    const int q0 = blockIdx.x * 64 + wave * 16;

    __shared__ alignas(16) u16 Vt[4][64][32];   // [wave][col][key]
    __shared__ alignas(16) u16 P1s[4][16][32];  // [wave][qrow][key]
    __shared__ alignas(16) u16 P2s[4][16][32];

    // lambda (computed redundantly; tiny)
    float s1 = 0.f, s2 = 0.f;
#pragma unroll
    for (int i = 0; i < 32; ++i) { s1 += lq1[i] * lk1[i]; s2 += lq2[i] * lk2[i]; }
    const float lam = __expf(s1) - __expf(s2) + LAMBDA_INIT;

    const u16* Qbase = Qb + (size_t)b * NQ * DIMC;
    const u16* Kbase = Kb + (size_t)b * NK * DIMC;
    const u16* Vbase = Vb + (size_t)b * NK * DIMC;

    const bf16x8 q1f = *(const bf16x8*)(Qbase + (size_t)(q0 + l15) * DIMC + h * 32 + 8 * l4);
    const bf16x8 q2f = *(const bf16x8*)(Qbase + (size_t)(q0 + l15) * DIMC + 512 + h * 32 + 8 * l4);

    float m1[4], d1[4], m2[4], d2[4];
    f32x4 acc1[4], acc2[4];
    f32x4 zf = {0.f, 0.f, 0.f, 0.f};
#pragma unroll
    for (int r = 0; r < 4; ++r) { m1[r] = -1e30f; d1[r] = 0.f; m2[r] = -1e30f; d2[r] = 0.f; }
#pragma unroll
    for (int t = 0; t < 4; ++t) { acc1[t] = zf; acc2[t] = zf; }

    for (int kv0 = 0; kv0 < NK; kv0 += 32) {
        // stage V tile transposed: Vt[col][key]
#pragma unroll
        for (int c = 0; c < 4; ++c) {
            const int chunk = lane + 64 * c;       // 0..255
            const int key = chunk >> 3;            // 0..31
            const int cb = (chunk & 7) * 8;        // 0,8,...,56
            bf16x8 v = *(const bf16x8*)(Vbase + (size_t)(kv0 + key) * DIMC + h * 64 + cb);
#pragma unroll
            for (int j = 0; j < 8; ++j) Vt[wave][cb + j][key] = (u16)v[j];
        }

        // scores: two 16x16 tiles per attention (KV tile = 32 keys)
        f32x4 sc1[2], sc2[2];
#pragma unroll
        for (int sub = 0; sub < 2; ++sub) {
            const int krow = kv0 + sub * 16 + l15;
            bf16x8 k1f = *(const bf16x8*)(Kbase + (size_t)krow * DIMC + h * 32 + 8 * l4);
            bf16x8 k2f = *(const bf16x8*)(Kbase + (size_t)krow * DIMC + 512 + h * 32 + 8 * l4);
            sc1[sub] = __builtin_amdgcn_mfma_f32_16x16x32_bf16(q1f, k1f, zf, 0, 0, 0);
            sc2[sub] = __builtin_amdgcn_mfma_f32_16x16x32_bf16(q2f, k2f, zf, 0, 0, 0);
        }

        // online softmax for both attentions; write P (bf16) to LDS
#pragma unroll
        for (int r = 0; r < 4; ++r) {
            // attn 1
            {
                float a = sc1[0][r] * SCALE_, bb = sc1[1][r] * SCALE_;
                float t = fmaxf(a, bb);
                t = fmaxf(t, __shfl_xor(t, 1)); t = fmaxf(t, __shfl_xor(t, 2));
                t = fmaxf(t, __shfl_xor(t, 4)); t = fmaxf(t, __shfl_xor(t, 8));
                const float nm = fmaxf(m1[r], t);
                const float alpha = __expf(m1[r] - nm);
                m1[r] = nm;
                const float p0 = __expf(a - nm), p1 = __expf(bb - nm);
                float rs = p0 + p1;
                rs += __shfl_xor(rs, 1); rs += __shfl_xor(rs, 2);
                rs += __shfl_xor(rs, 4); rs += __shfl_xor(rs, 8);
                d1[r] = d1[r] * alpha + rs;
#pragma unroll
                for (int t4 = 0; t4 < 4; ++t4) acc1[t4][r] *= alpha;
                P1s[wave][l4 * 4 + r][l15] = f2bf(p0);
                P1s[wave][l4 * 4 + r][16 + l15] = f2bf(p1);
            }
            // attn 2
            {
                float a = sc2[0][r] * SCALE_, bb = sc2[1][r] * SCALE_;
                float t = fmaxf(a, bb);
                t = fmaxf(t, __shfl_xor(t, 1)); t = fmaxf(t, __shfl_xor(t, 2));
                t = fmaxf(t, __shfl_xor(t, 4)); t = fmaxf(t, __shfl_xor(t, 8));
                const float nm = fmaxf(m2[r], t);
                const float alpha = __expf(m2[r] - nm);
                m2[r] = nm;
                const float p0 = __expf(a - nm), p1 = __expf(bb - nm);
                float rs = p0 + p1;
                rs += __shfl_xor(rs, 1); rs += __shfl_xor(rs, 2);
                rs += __shfl_xor(rs, 4); rs += __shfl_xor(rs, 8);
                d2[r] = d2[r] * alpha + rs;
#pragma unroll
                for (int t4 = 0; t4 < 4; ++t4) acc2[t4][r] *= alpha;
                P2s[wave][l4 * 4 + r][l15] = f2bf(p0);
                P2s[wave][l4 * 4 + r][16 + l15] = f2bf(p1);
            }
        }

        __syncthreads();  // uniform; makes Vt/P LDS writes visible

        // PV: P (16x32) @ V (32x64)
        const bf16x8 p1a = *(const bf16x8*)&P1s[wave][l15][8 * l4];
        const bf16x8 p2a = *(const bf16x8*)&P2s[wave][l15][8 * l4];
#pragma unroll
        for (int t = 0; t < 4; ++t) {
            bf16x8 vb = *(const bf16x8*)&Vt[wave][t * 16 + l15][8 * l4];
            acc1[t] = __builtin_amdgcn_mfma_f32_16x16x32_bf16(p1a, vb, acc1[t], 0, 0, 0);
            acc2[t] = __builtin_amdgcn_mfma_f32_16x16x32_bf16(p2a, vb, acc2[t], 0, 0, 0);
        }
        __syncthreads();
    }

    // epilogue: combine, RMS norm over 64, subln_w, (1-lambda_init)
    float inv1[4], inv2[4];
#pragma unroll
    for (int r = 0; r < 4; ++r) { inv1[r] = 1.f / d1[r]; inv2[r] = 1.f / d2[r]; }

    float vals[4][4];  // [t][r]
    float ss[4] = {0.f, 0.f, 0.f, 0.f};
#pragma unroll
    for (int t = 0; t < 4; ++t)
#pragma unroll
        for (int r = 0; r < 4; ++r) {
            const float v = acc1[t][r] * inv1[r] - lam * (acc2[t][r] * inv2[r]);
            vals[t][r] = v;
            ss[r] += v * v;
        }
#pragma unroll
    for (int r = 0; r < 4; ++r) {
        float s = ss[r];
        s += __shfl_xor(s, 1); s += __shfl_xor(s, 2);
        s += __shfl_xor(s, 4); s += __shfl_xor(s, 8);
        ss[r] = rsqrtf(s * (1.f / 64.f) + EPS_) * ONE_MINUS_LI;
    }
#pragma unroll
    for (int t = 0; t < 4; ++t)
#pragma unroll
        for (int r = 0; r < 4; ++r) {
            const int col = t * 16 + l15;
            const int row = q0 + l4 * 4 + r;
            const float o = vals[t][r] * ss[r] * subln[col];
            X2[(size_t)(b * NQ + row) * DIMC + h * 64 + col] = f2bf(o);
        }
}

extern "C" void kernel_launch(void* const* d_in, const int* in_sizes, int n_in,
                              void* d_out, int out_size, void* d_ws, size_t ws_size,
                              hipStream_t stream) {
    const float* query = (const float*)d_in[0];
    const float* key_  = (const float*)d_in[1];
    const float* value = (const float*)d_in[2];
    const float* Wq    = (const float*)d_in[3];
    const float* Wk    = (const float*)d_in[4];
    const float* Wv    = (const float*)d_in[5];
    const float* Wp    = (const float*)d_in[6];
    const float* bp    = (const float*)d_in[7];
    const float* lq1   = (const float*)d_in[8];
    const float* lk1   = (const float*)d_in[9];
    const float* lq2   = (const float*)d_in[10];
    const float* lk2   = (const float*)d_in[11];
    const float* subln = (const float*)d_in[12];
    float* out = (float*)d_out;

    u16* Qb = (u16*)d_ws;
    u16* Kb = Qb + (size_t)4096 * 1024;
    u16* Vb = Kb + (size_t)4096 * 1024;
    u16* X2 = Vb + (size_t)4096 * 1024;

    dim3 gg(64, 16, 1), bb(256, 1, 1);
    hipLaunchKernelGGL((gemm_bt_kernel<0, 1>), gg, bb, 0, stream, query, Wq, Qb, nullptr, 4096, 1024, 1024);
    hipLaunchKernelGGL((gemm_bt_kernel<0, 1>), gg, bb, 0, stream, key_,  Wk, Kb, nullptr, 4096, 1024, 1024);
    hipLaunchKernelGGL((gemm_bt_kernel<0, 1>), gg, bb, 0, stream, value, Wv, Vb, nullptr, 4096, 1024, 1024);

    dim3 ga(32, 16, 2);
    hipLaunchKernelGGL(attn_kernel, ga, bb, 0, stream, Qb, Kb, Vb, lq1, lk1, lq2, lk2, subln, X2);

    hipLaunchKernelGGL((gemm_bt_kernel<1, 0>), gg, bb, 0, stream, X2, Wp, out, bp, 4096, 1024, 1024);
}

// Round 4
// 804.910 us; speedup vs baseline: 1.2864x; 1.2864x over previous
//
#include <hip/hip_runtime.h>

using u16 = unsigned short;
using u32 = unsigned int;
typedef __attribute__((ext_vector_type(8))) short bf16x8;
typedef __attribute__((ext_vector_type(4))) float f32x4;
typedef __attribute__((ext_vector_type(4))) float f4;

#define DIMC 1024
#define NQ 2048
#define NK 2048

static constexpr float LAMBDA_INIT = 0.6192834728526787f;  // 0.8 - 0.6*exp(-1.2)
static constexpr float ONE_MINUS_LI = 1.0f - 0.6192834728526787f;
static constexpr float SCALE_ = 0.17677669529663687f;      // 32^-0.5
static constexpr float EPS_ = 1e-5f;

__device__ __forceinline__ u16 f2bf(float f) {
    union { float f; unsigned u; } v; v.f = f;
    unsigned u = v.u;
    unsigned r = (u + 0x7FFFu + ((u >> 16) & 1u)) >> 16;
    return (u16)r;
}

__device__ __forceinline__ u32 packbf(float a, float b) {
    return (u32)f2bf(a) | ((u32)f2bf(b) << 16);
}

__device__ __forceinline__ bf16x8 load8f_bf(const float* p) {
    f4 a = *(const f4*)p;
    f4 b = *(const f4*)(p + 4);
    bf16x8 r;
    r[0] = (short)f2bf(a[0]); r[1] = (short)f2bf(a[1]);
    r[2] = (short)f2bf(a[2]); r[3] = (short)f2bf(a[3]);
    r[4] = (short)f2bf(b[0]); r[5] = (short)f2bf(b[1]);
    r[6] = (short)f2bf(b[2]); r[7] = (short)f2bf(b[3]);
    return r;
}

// C = A @ B^T.  A: M x K (f32 or bf16), B: N x K (f32). Output bf16*oscale or f32+bias.
template<int A_IS_BF16, int OUT_IS_BF16>
__global__ __launch_bounds__(256) void gemm_bt_kernel(
    const void* __restrict__ A_, const float* __restrict__ Bw,
    void* __restrict__ C_, const float* __restrict__ bias,
    int M, int N, int K, float oscale)
{
    const int lane = threadIdx.x & 63;
    const int wave = threadIdx.x >> 6;
    const int wr = wave >> 1, wc = wave & 1;
    const int l15 = lane & 15, l4 = lane >> 4;
    const int tm = blockIdx.x * 64, tn = blockIdx.y * 64;
    const int arow0 = tm + wr * 32, brow0 = tn + wc * 32;

    f32x4 acc[2][2];
    f32x4 zf = {0.f, 0.f, 0.f, 0.f};
    acc[0][0] = zf; acc[0][1] = zf; acc[1][0] = zf; acc[1][1] = zf;

    for (int k0 = 0; k0 < K; k0 += 32) {
        const int kk = k0 + 8 * l4;
        bf16x8 af[2], bfr[2];
#pragma unroll
        for (int i = 0; i < 2; ++i) {
            const int ar = arow0 + i * 16 + l15;
            if (A_IS_BF16)
                af[i] = *(const bf16x8*)((const u16*)A_ + (size_t)ar * K + kk);
            else
                af[i] = load8f_bf((const float*)A_ + (size_t)ar * K + kk);
            const int br = brow0 + i * 16 + l15;
            bfr[i] = load8f_bf(Bw + (size_t)br * K + kk);
        }
#pragma unroll
        for (int i = 0; i < 2; ++i)
#pragma unroll
            for (int j = 0; j < 2; ++j)
                acc[i][j] = __builtin_amdgcn_mfma_f32_16x16x32_bf16(af[i], bfr[j], acc[i][j], 0, 0, 0);
    }

#pragma unroll
    for (int i = 0; i < 2; ++i)
#pragma unroll
        for (int j = 0; j < 2; ++j)
#pragma unroll
            for (int r = 0; r < 4; ++r) {
                const int row = arow0 + i * 16 + l4 * 4 + r;
                const int col = brow0 + j * 16 + l15;
                const float v = acc[i][j][r];
                if (OUT_IS_BF16)
                    ((u16*)C_)[(size_t)row * N + col] = f2bf(v * oscale);
                else
                    ((float*)C_)[(size_t)row * N + col] = v + bias[col];
            }
}

// Differential flash attention + subln RMS-norm epilogue.
// Qb: bf16 [B*2048][1024] (pre-scaled by SCALE_), Kb: bf16 [B*2048][1024],
// Vt: bf16 [1024 dims][4096 tokens] (transposed V). X2 out: bf16 [B*2048][1024].
__global__ __launch_bounds__(256) void attn_kernel(
    const u16* __restrict__ Qb, const u16* __restrict__ Kb, const u16* __restrict__ Vt,
    const float* __restrict__ lq1, const float* __restrict__ lk1,
    const float* __restrict__ lq2, const float* __restrict__ lk2,
    const float* __restrict__ subln, u16* __restrict__ X2)
{
    const int lane = threadIdx.x & 63;
    const int wave = threadIdx.x >> 6;
    const int l15 = lane & 15, l4 = lane >> 4;
    const int b = blockIdx.z, h = blockIdx.y;
    const int q0 = blockIdx.x * 64 + wave * 16;

    // wave-private P tiles: [wave][attn][16 rows][64 keys] bf16, XOR-swizzled
    __shared__ alignas(16) u16 Ps[4][2][16 * 64];
    u16* P1 = &Ps[wave][0][0];
    u16* P2 = &Ps[wave][1][0];

    float s1 = 0.f, s2 = 0.f;
#pragma unroll
    for (int i = 0; i < 32; ++i) { s1 += lq1[i] * lk1[i]; s2 += lq2[i] * lk2[i]; }
    const float lam = __expf(s1) - __expf(s2) + LAMBDA_INIT;

    const u16* Qbase = Qb + (size_t)b * NQ * DIMC;
    const u16* Kbase = Kb + (size_t)b * NK * DIMC;
    const u16* Vbase = Vt + (size_t)h * 64 * 4096 + (size_t)b * 2048;

    // Q as B-operand fragments (pre-scaled by SCALE_ in projection)
    const bf16x8 q1f = *(const bf16x8*)(Qbase + (size_t)(q0 + l15) * DIMC + h * 32 + 8 * l4);
    const bf16x8 q2f = *(const bf16x8*)(Qbase + (size_t)(q0 + l15) * DIMC + 512 + h * 32 + 8 * l4);

    // per-lane softmax state: row = l15 (one q-row per lane)
    float m1 = -1e30f, d1 = 0.f, m2 = -1e30f, d2 = 0.f;
    f32x4 acc1[4], acc2[4];
    f32x4 zf = {0.f, 0.f, 0.f, 0.f};
#pragma unroll
    for (int t = 0; t < 4; ++t) { acc1[t] = zf; acc2[t] = zf; }

    const int wrow = l4 << 2;  // accumulator row base (l4*4 + r)

    for (int kv0 = 0; kv0 < NK; kv0 += 64) {
        // swapped QK^T: sc[s] = K_sub(s) . Q  -> D[key][qrow], lane: qrow=l15, keys = s*16 + l4*4 + r
        f32x4 sc1[4], sc2[4];
#pragma unroll
        for (int s = 0; s < 4; ++s) {
            const u16* kr = Kbase + (size_t)(kv0 + s * 16 + l15) * DIMC + 8 * l4;
            bf16x8 k1 = *(const bf16x8*)(kr + h * 32);
            bf16x8 k2 = *(const bf16x8*)(kr + 512 + h * 32);
            sc1[s] = __builtin_amdgcn_mfma_f32_16x16x32_bf16(k1, q1f, zf, 0, 0, 0);
            sc2[s] = __builtin_amdgcn_mfma_f32_16x16x32_bf16(k2, q2f, zf, 0, 0, 0);
        }

        // ---- softmax attn 1 ----
        {
            float pm = sc1[0][0];
#pragma unroll
            for (int s = 0; s < 4; ++s)
#pragma unroll
                for (int r = 0; r < 4; ++r) pm = fmaxf(pm, sc1[s][r]);
            pm = fmaxf(pm, __shfl_xor(pm, 16));
            pm = fmaxf(pm, __shfl_xor(pm, 32));
            const float mnew = fmaxf(m1, pm);
            const float alpha = __expf(m1 - mnew);
            m1 = mnew;
            float rs = 0.f;
            float p[4][4];
#pragma unroll
            for (int s = 0; s < 4; ++s)
#pragma unroll
                for (int r = 0; r < 4; ++r) { p[s][r] = __expf(sc1[s][r] - mnew); rs += p[s][r]; }
            rs += __shfl_xor(rs, 16);
            rs += __shfl_xor(rs, 32);
            d1 = d1 * alpha + rs;
#pragma unroll
            for (int s = 0; s < 4; ++s) {
                uint2 wv;
                wv.x = packbf(p[s][0], p[s][1]);
                wv.y = packbf(p[s][2], p[s][3]);
                const int idx = ((l15 << 6) + (s << 4) + (l4 << 2)) ^ ((l15 & 7) << 3);
                *(uint2*)&P1[idx] = wv;
            }
            float ar[4];
#pragma unroll
            for (int r = 0; r < 4; ++r) ar[r] = __shfl(alpha, wrow + r);
#pragma unroll
            for (int t = 0; t < 4; ++t)
#pragma unroll
                for (int r = 0; r < 4; ++r) acc1[t][r] *= ar[r];
        }
        // ---- softmax attn 2 ----
        {
            float pm = sc2[0][0];
#pragma unroll
            for (int s = 0; s < 4; ++s)
#pragma unroll
                for (int r = 0; r < 4; ++r) pm = fmaxf(pm, sc2[s][r]);
            pm = fmaxf(pm, __shfl_xor(pm, 16));
            pm = fmaxf(pm, __shfl_xor(pm, 32));
            const float mnew = fmaxf(m2, pm);
            const float alpha = __expf(m2 - mnew);
            m2 = mnew;
            float rs = 0.f;
            float p[4][4];
#pragma unroll
            for (int s = 0; s < 4; ++s)
#pragma unroll
                for (int r = 0; r < 4; ++r) { p[s][r] = __expf(sc2[s][r] - mnew); rs += p[s][r]; }
            rs += __shfl_xor(rs, 16);
            rs += __shfl_xor(rs, 32);
            d2 = d2 * alpha + rs;
#pragma unroll
            for (int s = 0; s < 4; ++s) {
                uint2 wv;
                wv.x = packbf(p[s][0], p[s][1]);
                wv.y = packbf(p[s][2], p[s][3]);
                const int idx = ((l15 << 6) + (s << 4) + (l4 << 2)) ^ ((l15 & 7) << 3);
                *(uint2*)&P2[idx] = wv;
            }
            float ar[4];
#pragma unroll
            for (int r = 0; r < 4; ++r) ar[r] = __shfl(alpha, wrow + r);
#pragma unroll
            for (int t = 0; t < 4; ++t)
#pragma unroll
                for (int r = 0; r < 4; ++r) acc2[t][r] *= ar[r];
        }

        // ---- PV: acc += P(16x64) @ V^T fragments ----
#pragma unroll
        for (int kc = 0; kc < 2; ++kc) {
            const int ridx = ((l15 << 6) + (kc << 5) + (l4 << 3)) ^ ((l15 & 7) << 3);
            const bf16x8 p1a = *(const bf16x8*)&P1[ridx];
            const bf16x8 p2a = *(const bf16x8*)&P2[ridx];
#pragma unroll
            for (int t = 0; t < 4; ++t) {
                bf16x8 vb = *(const bf16x8*)(Vbase + (size_t)(t * 16 + l15) * 4096 + kv0 + kc * 32 + 8 * l4);
                acc1[t] = __builtin_amdgcn_mfma_f32_16x16x32_bf16(p1a, vb, acc1[t], 0, 0, 0);
                acc2[t] = __builtin_amdgcn_mfma_f32_16x16x32_bf16(p2a, vb, acc2[t], 0, 0, 0);
            }
        }
    }

    // epilogue: combine, RMS norm over 64 dims, subln_w, (1-lambda_init)
    float i1[4], i2[4];
#pragma unroll
    for (int r = 0; r < 4; ++r) {
        i1[r] = 1.f / __shfl(d1, wrow + r);
        i2[r] = 1.f / __shfl(d2, wrow + r);
    }

    float vals[4][4];
    float ss[4] = {0.f, 0.f, 0.f, 0.f};
#pragma unroll
    for (int t = 0; t < 4; ++t)
#pragma unroll
        for (int r = 0; r < 4; ++r) {
            const float v = acc1[t][r] * i1[r] - lam * (acc2[t][r] * i2[r]);
            vals[t][r] = v;
            ss[r] += v * v;
        }
#pragma unroll
    for (int r = 0; r < 4; ++r) {
        float s = ss[r];
        s += __shfl_xor(s, 1); s += __shfl_xor(s, 2);
        s += __shfl_xor(s, 4); s += __shfl_xor(s, 8);
        ss[r] = rsqrtf(s * (1.f / 64.f) + EPS_) * ONE_MINUS_LI;
    }
#pragma unroll
    for (int t = 0; t < 4; ++t)
#pragma unroll
        for (int r = 0; r < 4; ++r) {
            const int col = t * 16 + l15;
            const int row = q0 + wrow + r;
            const float o = vals[t][r] * ss[r] * subln[col];
            X2[(size_t)(b * NQ + row) * DIMC + h * 64 + col] = f2bf(o);
        }
}

extern "C" void kernel_launch(void* const* d_in, const int* in_sizes, int n_in,
                              void* d_out, int out_size, void* d_ws, size_t ws_size,
                              hipStream_t stream) {
    const float* query = (const float*)d_in[0];
    const float* key_  = (const float*)d_in[1];
    const float* value = (const float*)d_in[2];
    const float* Wq    = (const float*)d_in[3];
    const float* Wk    = (const float*)d_in[4];
    const float* Wv    = (const float*)d_in[5];
    const float* Wp    = (const float*)d_in[6];
    const float* bp    = (const float*)d_in[7];
    const float* lq1   = (const float*)d_in[8];
    const float* lk1   = (const float*)d_in[9];
    const float* lq2   = (const float*)d_in[10];
    const float* lk2   = (const float*)d_in[11];
    const float* subln = (const float*)d_in[12];
    float* out = (float*)d_out;

    u16* Qb = (u16*)d_ws;
    u16* Kb = Qb + (size_t)4096 * 1024;
    u16* Vt = Kb + (size_t)4096 * 1024;   // [1024 dims][4096 tokens]
    u16* X2 = Vt + (size_t)4096 * 1024;

    dim3 bb(256, 1, 1);
    dim3 gg(64, 16, 1);
    // Q projection, pre-scaled by SCALE_
    hipLaunchKernelGGL((gemm_bt_kernel<0, 1>), gg, bb, 0, stream, query, Wq, Qb, nullptr, 4096, 1024, 1024, SCALE_);
    hipLaunchKernelGGL((gemm_bt_kernel<0, 1>), gg, bb, 0, stream, key_,  Wk, Kb, nullptr, 4096, 1024, 1024, 1.0f);
    // V projection with swapped operands: C[dim][token] = Wv . value^T  (free transpose)
    dim3 gv(16, 64, 1);
    hipLaunchKernelGGL((gemm_bt_kernel<0, 1>), gv, bb, 0, stream, Wv, value, Vt, nullptr, 1024, 4096, 1024, 1.0f);

    dim3 ga(32, 16, 2);
    hipLaunchKernelGGL(attn_kernel, ga, bb, 0, stream, Qb, Kb, Vt, lq1, lk1, lq2, lk2, subln, X2);

    hipLaunchKernelGGL((gemm_bt_kernel<1, 0>), gg, bb, 0, stream, X2, Wp, out, bp, 4096, 1024, 1024, 1.0f);
}

// Round 5
// 528.730 us; speedup vs baseline: 1.9583x; 1.5223x over previous
//
#include <hip/hip_runtime.h>

using u16 = unsigned short;
using u32 = unsigned int;
typedef __attribute__((ext_vector_type(8))) short bf16x8;
typedef __attribute__((ext_vector_type(4))) float f32x4;
typedef __attribute__((ext_vector_type(4))) float f4;

#define DIMC 1024
#define NQ 2048
#define NK 2048

static constexpr float LAMBDA_INIT = 0.6192834728526787f;  // 0.8 - 0.6*exp(-1.2)
static constexpr float ONE_MINUS_LI = 1.0f - 0.6192834728526787f;
static constexpr float SCALE_ = 0.17677669529663687f;      // 32^-0.5
static constexpr float LOG2E_ = 1.4426950408889634f;
static constexpr float EPS_ = 1e-5f;

__device__ __forceinline__ u16 f2bf(float f) {
    union { float f; unsigned u; } v; v.f = f;
    unsigned u = v.u;
    unsigned r = (u + 0x7FFFu + ((u >> 16) & 1u)) >> 16;
    return (u16)r;
}

// truncating pack of two f32 -> 2x bf16 (cheap; P is ratio-normalized so rel err 2^-8 cancels)
__device__ __forceinline__ u32 packbf_trunc(float a, float b) {
    return (__float_as_uint(a) >> 16) | (__float_as_uint(b) & 0xFFFF0000u);
}

// ---------------- f32 -> bf16 conversion (memory-bound) ----------------
__global__ __launch_bounds__(256) void cvt_kernel(const float* __restrict__ s,
                                                  u16* __restrict__ d, int n) {
    const int i = (blockIdx.x * 256 + threadIdx.x) * 8;
    if (i >= n) return;
    f4 a = *(const f4*)(s + i);
    f4 b = *(const f4*)(s + i + 4);
    bf16x8 r;
    r[0] = (short)f2bf(a[0]); r[1] = (short)f2bf(a[1]);
    r[2] = (short)f2bf(a[2]); r[3] = (short)f2bf(a[3]);
    r[4] = (short)f2bf(b[0]); r[5] = (short)f2bf(b[1]);
    r[6] = (short)f2bf(b[2]); r[7] = (short)f2bf(b[3]);
    *(bf16x8*)(d + i) = r;
}

// ---------------- 128x128-tile bf16 GEMM, direct global fragment loads ----------------
// C = A @ B^T.  A: M x 1024 bf16, B: N x 1024 bf16.
template<int OUT_MODE>  // 0: bf16 * osc, 1: f32 + bias
__device__ __forceinline__ void gemm_tile(
    const u16* __restrict__ A, const u16* __restrict__ B,
    void* __restrict__ C, const float* __restrict__ bias,
    int tm, int tn, int N, float osc)
{
    constexpr int K = 1024;
    const int lane = threadIdx.x & 63;
    const int wave = threadIdx.x >> 6;
    const int wr = wave >> 1, wc = wave & 1;
    const int l15 = lane & 15, l4 = lane >> 4;
    const int arow0 = tm + wr * 64, brow0 = tn + wc * 64;

    const u16* Ab = A + (size_t)(arow0 + l15) * K + 8 * l4;
    const u16* Bb = B + (size_t)(brow0 + l15) * K + 8 * l4;

    f32x4 acc[4][4];
    f32x4 zf = {0.f, 0.f, 0.f, 0.f};
#pragma unroll
    for (int i = 0; i < 4; ++i)
#pragma unroll
        for (int j = 0; j < 4; ++j) acc[i][j] = zf;

#pragma unroll 2
    for (int k0 = 0; k0 < K; k0 += 32) {
        bf16x8 af[4], bfr[4];
#pragma unroll
        for (int i = 0; i < 4; ++i) af[i] = *(const bf16x8*)(Ab + (size_t)i * 16 * K + k0);
#pragma unroll
        for (int j = 0; j < 4; ++j) bfr[j] = *(const bf16x8*)(Bb + (size_t)j * 16 * K + k0);
#pragma unroll
        for (int i = 0; i < 4; ++i)
#pragma unroll
            for (int j = 0; j < 4; ++j)
                acc[i][j] = __builtin_amdgcn_mfma_f32_16x16x32_bf16(af[i], bfr[j], acc[i][j], 0, 0, 0);
    }

#pragma unroll
    for (int i = 0; i < 4; ++i)
#pragma unroll
        for (int j = 0; j < 4; ++j)
#pragma unroll
            for (int r = 0; r < 4; ++r) {
                const int row = arow0 + i * 16 + l4 * 4 + r;
                const int col = brow0 + j * 16 + l15;
                const float v = acc[i][j][r];
                if (OUT_MODE == 0)
                    ((u16*)C)[(size_t)row * N + col] = f2bf(v * osc);
                else
                    ((float*)C)[(size_t)row * N + col] = v + bias[col];
            }
}

// fused Q/K/V projections (z selects), XCD-swizzled
__global__ __launch_bounds__(256) void qkv_gemm_kernel(
    const u16* __restrict__ qa, const u16* __restrict__ wq, u16* __restrict__ qo,
    const u16* __restrict__ ka, const u16* __restrict__ wk, u16* __restrict__ ko,
    const u16* __restrict__ wv, const u16* __restrict__ va, u16* __restrict__ vo,
    float qosc)
{
    int id = blockIdx.x + 8 * (blockIdx.y + 32 * blockIdx.z);  // 768 blocks
    id = (id & 7) * 96 + (id >> 3);                             // XCD-contiguous chunks
    const int x = id & 7, y = (id >> 3) & 31, z = id >> 8;

    if (z == 0)      gemm_tile<0>(qa, wq, qo, nullptr, y * 128, x * 128, 1024, qosc);
    else if (z == 1) gemm_tile<0>(ka, wk, ko, nullptr, y * 128, x * 128, 1024, 1.0f);
    else             gemm_tile<0>(wv, va, vo, nullptr, x * 128, y * 128, 4096, 1.0f);
}

__global__ __launch_bounds__(256) void out_gemm_kernel(
    const u16* __restrict__ A, const u16* __restrict__ Bw,
    float* __restrict__ C, const float* __restrict__ bias)
{
    int id = blockIdx.x + 8 * blockIdx.y;  // 256 blocks
    id = (id & 7) * 32 + (id >> 3);
    const int x = id & 7, y = id >> 3;
    gemm_tile<1>(A, Bw, C, bias, y * 128, x * 128, 1024, 1.0f);
}

// ---------------- differential flash attention + subln RMS epilogue ----------------
// Qb: bf16 (pre-scaled by SCALE*log2e), Kb: bf16, Vt: bf16 [1024 dims][4096 tokens].
__global__ __launch_bounds__(256) void attn_kernel(
    const u16* __restrict__ Qb, const u16* __restrict__ Kb, const u16* __restrict__ Vt,
    const float* __restrict__ lq1, const float* __restrict__ lk1,
    const float* __restrict__ lq2, const float* __restrict__ lk2,
    const float* __restrict__ subln, u16* __restrict__ X2)
{
    const int lane = threadIdx.x & 63;
    const int wave = threadIdx.x >> 6;
    const int l15 = lane & 15, l4 = lane >> 4;

    int id = blockIdx.x + 32 * (blockIdx.y + 16 * blockIdx.z);  // 1024 blocks
    id = (id & 7) * 128 + (id >> 3);                            // 4 (b,h) groups per XCD
    const int qt = id & 31, h = (id >> 5) & 15, b = id >> 9;
    const int q0 = qt * 64 + wave * 16;

    __shared__ alignas(16) u16 Ps[4][2][16 * 64];
    u16* P1 = &Ps[wave][0][0];
    u16* P2 = &Ps[wave][1][0];

    float s1 = 0.f, s2 = 0.f;
#pragma unroll
    for (int i = 0; i < 32; ++i) { s1 += lq1[i] * lk1[i]; s2 += lq2[i] * lk2[i]; }
    const float lam = __expf(s1) - __expf(s2) + LAMBDA_INIT;

    const u16* Qbase = Qb + (size_t)b * NQ * DIMC;
    const u16* Kbase = Kb + (size_t)b * NK * DIMC;
    const u16* Vbase = Vt + (size_t)h * 64 * 4096 + (size_t)b * 2048;

    const bf16x8 q1f = *(const bf16x8*)(Qbase + (size_t)(q0 + l15) * DIMC + h * 32 + 8 * l4);
    const bf16x8 q2f = *(const bf16x8*)(Qbase + (size_t)(q0 + l15) * DIMC + 512 + h * 32 + 8 * l4);

    float m1 = -1e30f, d1 = 0.f, m2 = -1e30f, d2 = 0.f;
    f32x4 acc1[4], acc2[4];
    f32x4 zf = {0.f, 0.f, 0.f, 0.f};
#pragma unroll
    for (int t = 0; t < 4; ++t) { acc1[t] = zf; acc2[t] = zf; }

    const int wrow = l4 << 2;

    for (int kv0 = 0; kv0 < NK; kv0 += 64) {
        // swapped QK^T (scores already in log2 domain via Q pre-scale)
        f32x4 sc1[4], sc2[4];
#pragma unroll
        for (int s = 0; s < 4; ++s) {
            const u16* kr = Kbase + (size_t)(kv0 + s * 16 + l15) * DIMC + 8 * l4;
            bf16x8 k1 = *(const bf16x8*)(kr + h * 32);
            bf16x8 k2 = *(const bf16x8*)(kr + 512 + h * 32);
            sc1[s] = __builtin_amdgcn_mfma_f32_16x16x32_bf16(k1, q1f, zf, 0, 0, 0);
            sc2[s] = __builtin_amdgcn_mfma_f32_16x16x32_bf16(k2, q2f, zf, 0, 0, 0);
        }

        // ---- softmax attn 1 (defer-max, exp2) ----
        {
            float pm = sc1[0][0];
#pragma unroll
            for (int s = 0; s < 4; ++s)
#pragma unroll
                for (int r = 0; r < 4; ++r) pm = fmaxf(pm, sc1[s][r]);
            pm = fmaxf(pm, __shfl_xor(pm, 16));
            pm = fmaxf(pm, __shfl_xor(pm, 32));
            if (!__all(pm - m1 <= 8.f)) {
                const float mnew = fmaxf(m1, pm);
                const float alpha = __builtin_amdgcn_exp2f(m1 - mnew);
                m1 = mnew;
                d1 *= alpha;
                float ar[4];
#pragma unroll
                for (int r = 0; r < 4; ++r) ar[r] = __shfl(alpha, wrow + r);
#pragma unroll
                for (int t = 0; t < 4; ++t)
#pragma unroll
                    for (int r = 0; r < 4; ++r) acc1[t][r] *= ar[r];
            }
            float rs = 0.f;
            float p[4][4];
#pragma unroll
            for (int s = 0; s < 4; ++s)
#pragma unroll
                for (int r = 0; r < 4; ++r) {
                    p[s][r] = __builtin_amdgcn_exp2f(sc1[s][r] - m1);
                    rs += p[s][r];
                }
            rs += __shfl_xor(rs, 16);
            rs += __shfl_xor(rs, 32);
            d1 += rs;
#pragma unroll
            for (int s = 0; s < 4; ++s) {
                uint2 wv;
                wv.x = packbf_trunc(p[s][0], p[s][1]);
                wv.y = packbf_trunc(p[s][2], p[s][3]);
                const int idx = ((l15 << 6) + (s << 4) + (l4 << 2)) ^ ((l15 & 7) << 3);
                *(uint2*)&P1[idx] = wv;
            }
        }
        // ---- softmax attn 2 ----
        {
            float pm = sc2[0][0];
#pragma unroll
            for (int s = 0; s < 4; ++s)
#pragma unroll
                for (int r = 0; r < 4; ++r) pm = fmaxf(pm, sc2[s][r]);
            pm = fmaxf(pm, __shfl_xor(pm, 16));
            pm = fmaxf(pm, __shfl_xor(pm, 32));
            if (!__all(pm - m2 <= 8.f)) {
                const float mnew = fmaxf(m2, pm);
                const float alpha = __builtin_amdgcn_exp2f(m2 - mnew);
                m2 = mnew;
                d2 *= alpha;
                float ar[4];
#pragma unroll
                for (int r = 0; r < 4; ++r) ar[r] = __shfl(alpha, wrow + r);
#pragma unroll
                for (int t = 0; t < 4; ++t)
#pragma unroll
                    for (int r = 0; r < 4; ++r) acc2[t][r] *= ar[r];
            }
            float rs = 0.f;
            float p[4][4];
#pragma unroll
            for (int s = 0; s < 4; ++s)
#pragma unroll
                for (int r = 0; r < 4; ++r) {
                    p[s][r] = __builtin_amdgcn_exp2f(sc2[s][r] - m2);
                    rs += p[s][r];
                }
            rs += __shfl_xor(rs, 16);
            rs += __shfl_xor(rs, 32);
            d2 += rs;
#pragma unroll
            for (int s = 0; s < 4; ++s) {
                uint2 wv;
                wv.x = packbf_trunc(p[s][0], p[s][1]);
                wv.y = packbf_trunc(p[s][2], p[s][3]);
                const int idx = ((l15 << 6) + (s << 4) + (l4 << 2)) ^ ((l15 & 7) << 3);
                *(uint2*)&P2[idx] = wv;
            }
        }

        // ---- PV ----
#pragma unroll
        for (int kc = 0; kc < 2; ++kc) {
            const int ridx = ((l15 << 6) + (kc << 5) + (l4 << 3)) ^ ((l15 & 7) << 3);
            const bf16x8 p1a = *(const bf16x8*)&P1[ridx];
            const bf16x8 p2a = *(const bf16x8*)&P2[ridx];
#pragma unroll
            for (int t = 0; t < 4; ++t) {
                bf16x8 vb = *(const bf16x8*)(Vbase + (size_t)(t * 16 + l15) * 4096 + kv0 + kc * 32 + 8 * l4);
                acc1[t] = __builtin_amdgcn_mfma_f32_16x16x32_bf16(p1a, vb, acc1[t], 0, 0, 0);
                acc2[t] = __builtin_amdgcn_mfma_f32_16x16x32_bf16(p2a, vb, acc2[t], 0, 0, 0);
            }
        }
    }

    // epilogue
    float i1[4], i2[4];
#pragma unroll
    for (int r = 0; r < 4; ++r) {
        i1[r] = 1.f / __shfl(d1, wrow + r);
        i2[r] = 1.f / __shfl(d2, wrow + r);
    }

    float vals[4][4];
    float ss[4] = {0.f, 0.f, 0.f, 0.f};
#pragma unroll
    for (int t = 0; t < 4; ++t)
#pragma unroll
        for (int r = 0; r < 4; ++r) {
            const float v = acc1[t][r] * i1[r] - lam * (acc2[t][r] * i2[r]);
            vals[t][r] = v;
            ss[r] += v * v;
        }
#pragma unroll
    for (int r = 0; r < 4; ++r) {
        float s = ss[r];
        s += __shfl_xor(s, 1); s += __shfl_xor(s, 2);
        s += __shfl_xor(s, 4); s += __shfl_xor(s, 8);
        ss[r] = rsqrtf(s * (1.f / 64.f) + EPS_) * ONE_MINUS_LI;
    }
#pragma unroll
    for (int t = 0; t < 4; ++t)
#pragma unroll
        for (int r = 0; r < 4; ++r) {
            const int col = t * 16 + l15;
            const int row = q0 + wrow + r;
            const float o = vals[t][r] * ss[r] * subln[col];
            X2[(size_t)(b * NQ + row) * DIMC + h * 64 + col] = f2bf(o);
        }
}

extern "C" void kernel_launch(void* const* d_in, const int* in_sizes, int n_in,
                              void* d_out, int out_size, void* d_ws, size_t ws_size,
                              hipStream_t stream) {
    const float* query = (const float*)d_in[0];
    const float* key_  = (const float*)d_in[1];
    const float* value = (const float*)d_in[2];
    const float* Wq    = (const float*)d_in[3];
    const float* Wk    = (const float*)d_in[4];
    const float* Wv    = (const float*)d_in[5];
    const float* Wp    = (const float*)d_in[6];
    const float* bp    = (const float*)d_in[7];
    const float* lq1   = (const float*)d_in[8];
    const float* lk1   = (const float*)d_in[9];
    const float* lq2   = (const float*)d_in[10];
    const float* lk2   = (const float*)d_in[11];
    const float* subln = (const float*)d_in[12];
    float* out = (float*)d_out;

    const size_t MB4 = (size_t)4096 * 1024;   // 4M elems
    const size_t MB1 = (size_t)1024 * 1024;   // 1M elems
    u16* base = (u16*)d_ws;
    u16* qbf = base;                 // 4M
    u16* kbf = qbf + MB4;            // 4M
    u16* vbf = kbf + MB4;            // 4M  (reused as X2 after QKV gemm)
    u16* wqb = vbf + MB4;            // 1M
    u16* wkb = wqb + MB1;            // 1M
    u16* wvb = wkb + MB1;            // 1M
    u16* wpb = wvb + MB1;            // 1M
    u16* Qb  = wpb + MB1;            // 4M
    u16* Kb  = Qb + MB4;             // 4M
    u16* Vt  = Kb + MB4;             // 4M  [1024 dims][4096 tokens]
    u16* X2  = vbf;                  // alias: vbf dead after qkv gemm

    dim3 bb(256, 1, 1);
    // f32 -> bf16 conversions
    hipLaunchKernelGGL(cvt_kernel, dim3(2048), bb, 0, stream, query, qbf, (int)MB4);
    hipLaunchKernelGGL(cvt_kernel, dim3(2048), bb, 0, stream, key_,  kbf, (int)MB4);
    hipLaunchKernelGGL(cvt_kernel, dim3(2048), bb, 0, stream, value, vbf, (int)MB4);
    hipLaunchKernelGGL(cvt_kernel, dim3(512),  bb, 0, stream, Wq, wqb, (int)MB1);
    hipLaunchKernelGGL(cvt_kernel, dim3(512),  bb, 0, stream, Wk, wkb, (int)MB1);
    hipLaunchKernelGGL(cvt_kernel, dim3(512),  bb, 0, stream, Wv, wvb, (int)MB1);
    hipLaunchKernelGGL(cvt_kernel, dim3(512),  bb, 0, stream, Wp, wpb, (int)MB1);

    // fused QKV projections (Q pre-scaled by SCALE*log2e); V transposed via swapped operands
    hipLaunchKernelGGL(qkv_gemm_kernel, dim3(8, 32, 3), bb, 0, stream,
                       qbf, wqb, Qb, kbf, wkb, Kb, wvb, vbf, Vt, SCALE_ * LOG2E_);

    hipLaunchKernelGGL(attn_kernel, dim3(32, 16, 2), bb, 0, stream,
                       Qb, Kb, Vt, lq1, lk1, lq2, lk2, subln, X2);

    hipLaunchKernelGGL(out_gemm_kernel, dim3(8, 32, 1), bb, 0, stream, X2, wpb, out, bp);
}